// Round 5
// baseline (1224.358 us; speedup 1.0000x reference)
//
#include <hip/hip_runtime.h>

#define NNODES 50000
#define EEDGES 800000
#define FIN 128
#define FH 128
#define FOUT 16
#define BN_EPS 1e-5f
#define NBIN 391           // ceil(50000/128) bins of 128 dst nodes
#define PCHUNK 8192        // edges per partition block
#define NPBLK 98           // ceil(800000/8192)

typedef short bf16x8 __attribute__((ext_vector_type(8)));
typedef float f32x4 __attribute__((ext_vector_type(4)));

__device__ inline unsigned short tobf16(float f) {
    unsigned int u = __float_as_uint(f);
    u += 0x7fffu + ((u >> 16) & 1u);   // RNE
    return (unsigned short)(u >> 16);
}
__device__ inline float frombf16(unsigned short h) {
    return __uint_as_float(((unsigned int)h) << 16);
}
__device__ inline unsigned packbf(float f0, float f1) {
    return (unsigned)tobf16(f0) | ((unsigned)tobf16(f1) << 16);
}
__device__ inline float lo16(unsigned u) { return __uint_as_float(u << 16); }
__device__ inline float hi16(unsigned u) { return __uint_as_float(u & 0xffff0000u); }

// ---------------- K1: pack x->bf16, W->bf16; deg + bin histogram ----------------
__global__ void pack_deg_kernel(const float* __restrict__ x,
                                const float* __restrict__ Wl1, const float* __restrict__ Wr1,
                                const float* __restrict__ Wl2, const float* __restrict__ Wr2,
                                const int* __restrict__ dst,
                                unsigned short* __restrict__ xb, unsigned short* __restrict__ wb,
                                int* __restrict__ deg, int* __restrict__ binCnt) {
    int idx = blockIdx.x * 256 + threadIdx.x;
    if (idx < NNODES * FIN) {
        xb[idx] = tobf16(x[idx]);
    } else if (idx < NNODES * FIN + 36864) {
        int w = idx - NNODES * FIN;
        float v;
        if (w < 16384) v = Wl1[w];
        else if (w < 32768) v = Wr1[w - 16384];
        else if (w < 34816) v = Wl2[w - 32768];
        else v = Wr2[w - 34816];
        wb[w] = tobf16(v);
    }
    if (idx < EEDGES) {
        int d = dst[idx];
        atomicAdd(&deg[d], 1);
        atomicAdd(&binCnt[d >> 7], 1);
    }
}

// ---------------- K2: scan 391 bin counts -> binStart, binFill ----------------
__global__ void scanbins_kernel(const int* __restrict__ binCnt,
                                int* __restrict__ binStart, int* __restrict__ binFill) {
    __shared__ int sh[512];
    int t = threadIdx.x;
    int v = (t < NBIN) ? binCnt[t] : 0;
    sh[t] = v;
    __syncthreads();
    for (int off = 1; off < 512; off <<= 1) {
        int u = (t >= off) ? sh[t - off] : 0;
        __syncthreads();
        sh[t] += u;
        __syncthreads();
    }
    if (t < NBIN) { binStart[t] = sh[t] - v; binFill[t] = sh[t] - v; }
}

// ---------------- K3: partition edges into bins (run-reserved, write-local) ----------------
__global__ void partition_kernel(const int* __restrict__ src, const int* __restrict__ dst,
                                 int* __restrict__ binFill, unsigned int* __restrict__ edgeBin) {
    __shared__ int hist[NBIN];
    __shared__ int runBase[NBIN];
    __shared__ int runFill[NBIN];
    int t = threadIdx.x;
    for (int i = t; i < NBIN; i += 256) { hist[i] = 0; runFill[i] = 0; }
    __syncthreads();
    int e0 = blockIdx.x * PCHUNK;
    for (int i = 0; i < PCHUNK / 256; ++i) {
        int e = e0 + i * 256 + t;
        if (e < EEDGES) atomicAdd(&hist[dst[e] >> 7], 1);
    }
    __syncthreads();
    for (int i = t; i < NBIN; i += 256) {
        int c = hist[i];
        if (c) runBase[i] = atomicAdd(&binFill[i], c);
    }
    __syncthreads();
    for (int i = 0; i < PCHUNK / 256; ++i) {
        int e = e0 + i * 256 + t;
        if (e < EEDGES) {
            int d = dst[e];
            int b = d >> 7;
            int off = atomicAdd(&runFill[b], 1);
            edgeBin[runBase[b] + off] = ((unsigned)(d & 127) << 17) | (unsigned)src[e];
        }
    }
}

// ---------------- K4: bin-local gather, 128 features (LDS fp32 accum) ----------------
__global__ void __launch_bounds__(256, 2)
gatherbin_kernel(const unsigned short* __restrict__ feat,
                 const unsigned int* __restrict__ edgeBin,
                 const int* __restrict__ binStart, const int* __restrict__ binCnt,
                 const int* __restrict__ deg, unsigned short* __restrict__ aggout) {
    __shared__ float accum[128 * 128];
    int t = threadIdx.x;
    for (int i = t; i < 16384; i += 256) accum[i] = 0.0f;
    __syncthreads();
    int b = blockIdx.x;
    int bs = binStart[b], cnt = binCnt[b];
    int w = t >> 6, lane = t & 63;
    const unsigned int* fp = (const unsigned int*)feat;
    for (int k = w * 4; k < cnt; k += 16) {
        int n = min(4, cnt - k);
        unsigned c0 = edgeBin[bs + k];
        unsigned c1 = (n > 1) ? edgeBin[bs + k + 1] : 0;
        unsigned c2 = (n > 2) ? edgeBin[bs + k + 2] : 0;
        unsigned c3 = (n > 3) ? edgeBin[bs + k + 3] : 0;
        unsigned u0 = fp[(size_t)(c0 & 0x1FFFF) * 64 + lane];
        unsigned u1 = (n > 1) ? fp[(size_t)(c1 & 0x1FFFF) * 64 + lane] : 0;
        unsigned u2 = (n > 2) ? fp[(size_t)(c2 & 0x1FFFF) * 64 + lane] : 0;
        unsigned u3 = (n > 3) ? fp[(size_t)(c3 & 0x1FFFF) * 64 + lane] : 0;
        float* a0 = &accum[(c0 >> 17) * 128 + 2 * lane];
        atomicAdd(a0, lo16(u0)); atomicAdd(a0 + 1, hi16(u0));
        if (n > 1) { float* a1 = &accum[(c1 >> 17) * 128 + 2 * lane];
                     atomicAdd(a1, lo16(u1)); atomicAdd(a1 + 1, hi16(u1)); }
        if (n > 2) { float* a2 = &accum[(c2 >> 17) * 128 + 2 * lane];
                     atomicAdd(a2, lo16(u2)); atomicAdd(a2 + 1, hi16(u2)); }
        if (n > 3) { float* a3 = &accum[(c3 >> 17) * 128 + 2 * lane];
                     atomicAdd(a3, lo16(u3)); atomicAdd(a3 + 1, hi16(u3)); }
    }
    __syncthreads();
    for (int i = t; i < 8192; i += 256) {
        int n = i >> 6, j = i & 63;
        int node = b * 128 + n;
        if (node < NNODES) {
            float inv = 1.0f / (float)max(deg[node], 1);
            ((unsigned int*)aggout)[(size_t)node * 64 + j] =
                packbf(accum[n * 128 + 2 * j] * inv, accum[n * 128 + 2 * j + 1] * inv);
        }
    }
}

// ---------------- K5: lin1 MFMA + fused BN column partials ----------------
__global__ void lin1_mfma(const unsigned short* __restrict__ aggb,
                          const unsigned short* __restrict__ xb,
                          const unsigned short* __restrict__ wl,
                          const unsigned short* __restrict__ wr,
                          const float* __restrict__ bias,
                          unsigned short* __restrict__ hb,
                          float* __restrict__ bnsum, float* __restrict__ bnsq) {
    __shared__ float bps[128];
    __shared__ float bpq[128];
    int tid = threadIdx.x;
    if (tid < 128) { bps[tid] = 0.0f; bpq[tid] = 0.0f; }
    __syncthreads();
    int wave = tid >> 6;
    int lane = tid & 63;
    int row0 = blockIdx.x * 64 + wave * 16;
    int lrow = lane & 15;
    int kg = lane >> 4;
    int arow = min(row0 + lrow, NNODES - 1);
    f32x4 acc[8] = {};
    #pragma unroll
    for (int ks = 0; ks < 4; ++ks) {
        bf16x8 a = *(const bf16x8*)(aggb + (size_t)arow * 128 + ks * 32 + kg * 8);
        #pragma unroll
        for (int nf = 0; nf < 8; ++nf) {
            bf16x8 b = *(const bf16x8*)(wl + (size_t)(nf * 16 + lrow) * 128 + ks * 32 + kg * 8);
            acc[nf] = __builtin_amdgcn_mfma_f32_16x16x32_bf16(a, b, acc[nf], 0, 0, 0);
        }
    }
    #pragma unroll
    for (int ks = 0; ks < 4; ++ks) {
        bf16x8 a = *(const bf16x8*)(xb + (size_t)arow * 128 + ks * 32 + kg * 8);
        #pragma unroll
        for (int nf = 0; nf < 8; ++nf) {
            bf16x8 b = *(const bf16x8*)(wr + (size_t)(nf * 16 + lrow) * 128 + ks * 32 + kg * 8);
            acc[nf] = __builtin_amdgcn_mfma_f32_16x16x32_bf16(a, b, acc[nf], 0, 0, 0);
        }
    }
    #pragma unroll
    for (int nf = 0; nf < 8; ++nf) {
        float b = bias[nf * 16 + lrow];
        float s = 0.0f, q = 0.0f;
        #pragma unroll
        for (int r = 0; r < 4; ++r) {
            int row = row0 + kg * 4 + r;
            if (row < NNODES) {
                float vr = frombf16(tobf16(acc[nf][r] + b));
                hb[(size_t)row * 128 + nf * 16 + lrow] = tobf16(vr);
                s += vr; q += vr * vr;
            }
        }
        s += __shfl_xor(s, 16); s += __shfl_xor(s, 32);
        q += __shfl_xor(q, 16); q += __shfl_xor(q, 32);
        if (lane < 16) {
            atomicAdd(&bps[nf * 16 + lane], s);
            atomicAdd(&bpq[nf * 16 + lane], q);
        }
    }
    __syncthreads();
    if (tid < 128) {
        atomicAdd(&bnsum[tid], bps[tid]);
        atomicAdd(&bnsq[tid], bpq[tid]);
    }
}

// ---------------- K6: BN apply + PReLU + residual (bf16 x), in place on hb ----------------
__global__ void bn_apply_kernel(unsigned short* __restrict__ hb,
                                const unsigned short* __restrict__ xb,
                                const float* __restrict__ gamma, const float* __restrict__ beta,
                                const float* __restrict__ aptr,
                                const float* __restrict__ bnsum, const float* __restrict__ bnsq) {
    int idx = blockIdx.x * 256 + threadIdx.x;
    if (idx >= NNODES * FH) return;
    int j = idx & 127;
    const float invN = 1.0f / (float)NNODES;
    float mean = bnsum[j] * invN;
    float var = bnsq[j] * invN - mean * mean;
    float istd = rsqrtf(var + BN_EPS);
    float v = frombf16(hb[idx]);
    v = gamma[j] * (v - mean) * istd + beta[j];
    float a = aptr[0];
    v = (v >= 0.0f) ? v : a * v;
    hb[idx] = tobf16(v + frombf16(xb[idx]));
}

// ---------------- K7: y2 = hb @ Wl2^T (bf16 out, [N,16]) ----------------
__global__ void lin2a_kernel(const unsigned short* __restrict__ hb,
                             const unsigned short* __restrict__ wl,
                             unsigned short* __restrict__ y2) {
    int wave = threadIdx.x >> 6;
    int lane = threadIdx.x & 63;
    int row0 = blockIdx.x * 64 + wave * 16;
    int lrow = lane & 15;
    int kg = lane >> 4;
    int arow = min(row0 + lrow, NNODES - 1);
    f32x4 acc = {};
    #pragma unroll
    for (int ks = 0; ks < 4; ++ks) {
        bf16x8 a = *(const bf16x8*)(hb + (size_t)arow * 128 + ks * 32 + kg * 8);
        bf16x8 b = *(const bf16x8*)(wl + (size_t)lrow * 128 + ks * 32 + kg * 8);
        acc = __builtin_amdgcn_mfma_f32_16x16x32_bf16(a, b, acc, 0, 0, 0);
    }
    #pragma unroll
    for (int r = 0; r < 4; ++r) {
        int row = row0 + kg * 4 + r;
        if (row < NNODES)
            y2[(size_t)row * 16 + lrow] = tobf16(acc[r]);
    }
}

// ---------------- K8: bin-local gather, 16 features ----------------
__global__ void gatherbin16_kernel(const unsigned short* __restrict__ y2,
                                   const unsigned int* __restrict__ edgeBin,
                                   const int* __restrict__ binStart, const int* __restrict__ binCnt,
                                   const int* __restrict__ deg, unsigned short* __restrict__ agg2) {
    __shared__ float accum[128 * 16];
    int t = threadIdx.x;
    for (int i = t; i < 2048; i += 256) accum[i] = 0.0f;
    __syncthreads();
    int b = blockIdx.x;
    int bs = binStart[b], cnt = binCnt[b];
    int w = t >> 6, lane = t & 63;
    int el = lane >> 3, j = lane & 7;
    const unsigned int* yp = (const unsigned int*)y2;
    for (int k = w * 8; k < cnt; k += 32) {
        int kk = k + el;
        if (kk < cnt) {
            unsigned c = edgeBin[bs + kk];
            unsigned u = yp[(size_t)(c & 0x1FFFF) * 8 + j];
            float* a = &accum[(c >> 17) * 16 + 2 * j];
            atomicAdd(a, lo16(u));
            atomicAdd(a + 1, hi16(u));
        }
    }
    __syncthreads();
    for (int i = t; i < 1024; i += 256) {
        int n = i >> 3, jj = i & 7;
        int node = b * 128 + n;
        if (node < NNODES) {
            float inv = 1.0f / (float)max(deg[node], 1);
            ((unsigned int*)agg2)[(size_t)node * 8 + jj] =
                packbf(accum[n * 16 + 2 * jj] * inv, accum[n * 16 + 2 * jj + 1] * inv);
        }
    }
}

// ---------------- K9: out = agg2 + hb@Wr2^T + bl2 -> log_softmax ----------------
__global__ void lin2b_kernel(const unsigned short* __restrict__ agg2,
                             const unsigned short* __restrict__ hb,
                             const unsigned short* __restrict__ wr,
                             const float* __restrict__ bias,
                             float* __restrict__ out) {
    int wave = threadIdx.x >> 6;
    int lane = threadIdx.x & 63;
    int row0 = blockIdx.x * 64 + wave * 16;
    int lrow = lane & 15;
    int kg = lane >> 4;
    int arow = min(row0 + lrow, NNODES - 1);
    f32x4 acc = {};
    #pragma unroll
    for (int ks = 0; ks < 4; ++ks) {
        bf16x8 a = *(const bf16x8*)(hb + (size_t)arow * 128 + ks * 32 + kg * 8);
        bf16x8 b = *(const bf16x8*)(wr + (size_t)lrow * 128 + ks * 32 + kg * 8);
        acc = __builtin_amdgcn_mfma_f32_16x16x32_bf16(a, b, acc, 0, 0, 0);
    }
    float bl = bias[lrow];
    #pragma unroll
    for (int r = 0; r < 4; ++r) {
        int row = row0 + kg * 4 + r;
        int rowc = min(row, NNODES - 1);
        float v = acc[r] + bl + frombf16(agg2[(size_t)rowc * 16 + lrow]);
        float m = v;
        for (int s = 1; s < 16; s <<= 1) m = fmaxf(m, __shfl_xor(m, s, 16));
        float e = expf(v - m);
        float se = e;
        for (int s = 1; s < 16; s <<= 1) se += __shfl_xor(se, s, 16);
        if (row < NNODES)
            out[(size_t)row * FOUT + lrow] = v - m - logf(se);
    }
}

extern "C" void kernel_launch(void* const* d_in, const int* in_sizes, int n_in,
                              void* d_out, int out_size, void* d_ws, size_t ws_size,
                              hipStream_t stream) {
    const float* x    = (const float*)d_in[0];
    const int*   ei   = (const int*)d_in[1];
    const int*   src  = ei;
    const int*   dst  = ei + EEDGES;
    const float* Wl1  = (const float*)d_in[2];
    const float* bl1  = (const float*)d_in[3];
    const float* Wr1  = (const float*)d_in[4];
    const float* Wl2  = (const float*)d_in[5];
    const float* bl2  = (const float*)d_in[6];
    const float* Wr2  = (const float*)d_in[7];
    const float* gamma= (const float*)d_in[8];
    const float* beta = (const float*)d_in[9];
    const float* a    = (const float*)d_in[10];
    float* out = (float*)d_out;

    char* W = (char*)d_ws;
    unsigned short* xb    = (unsigned short*)(W + 0);           // 12,800,000 B
    unsigned short* hb    = (unsigned short*)(W + 12800000);    // 12,800,000 B
    unsigned short* aggb  = (unsigned short*)(W + 25600000);    // 12,800,000 B (layer1)
    unsigned short* y2b   = (unsigned short*)(W + 25600000);    // 1,600,000 B (overlays aggb)
    unsigned short* agg2b = (unsigned short*)(W + 27200000);    // 1,600,000 B
    unsigned short* wb    = (unsigned short*)(W + 38400000);    // 73,728 B
    unsigned int*   edgeBin = (unsigned int*)(W + 38473728);    // 3,200,000 B
    int* deg      = (int*)(W + 41673728);                       // 200,000 B
    int* binCnt   = (int*)(W + 41873728);                       // 1,564 B
    float* bnsum  = (float*)(W + 41875292);                     // 512 B
    float* bnsq   = (float*)(W + 41875804);                     // 512 B
    int* binStart = (int*)(W + 41876316);                       // 1,564 B
    int* binFill  = (int*)(W + 41877880);                       // 1,564 B

    unsigned short* wl1b = wb;
    unsigned short* wr1b = wb + 16384;
    unsigned short* wl2b = wb + 32768;
    unsigned short* wr2b = wb + 34816;

    // zero deg + binCnt + bnsum + bnsq (contiguous: 202,588 B)
    hipMemsetAsync(deg, 0, (size_t)202588, stream);

    pack_deg_kernel<<<25145, 256, 0, stream>>>(x, Wl1, Wr1, Wl2, Wr2, dst, xb, wb, deg, binCnt);
    scanbins_kernel<<<1, 512, 0, stream>>>(binCnt, binStart, binFill);
    partition_kernel<<<NPBLK, 256, 0, stream>>>(src, dst, binFill, edgeBin);

    // layer 1
    gatherbin_kernel<<<NBIN, 256, 0, stream>>>(xb, edgeBin, binStart, binCnt, deg, aggb);
    lin1_mfma<<<782, 256, 0, stream>>>(aggb, xb, wl1b, wr1b, bl1, hb, bnsum, bnsq);
    bn_apply_kernel<<<25000, 256, 0, stream>>>(hb, xb, gamma, beta, a, bnsum, bnsq);

    // layer 2 (transform-then-aggregate: mean commutes with the linear map)
    lin2a_kernel<<<782, 256, 0, stream>>>(hb, wl2b, y2b);
    gatherbin16_kernel<<<NBIN, 256, 0, stream>>>(y2b, edgeBin, binStart, binCnt, deg, agg2b);
    lin2b_kernel<<<782, 256, 0, stream>>>(agg2b, hb, wr2b, bl2, out);
}

// Round 6
// 234.966 us; speedup vs baseline: 5.2108x; 5.2108x over previous
//
#include <hip/hip_runtime.h>

#define NNODES 50000
#define EEDGES 800000
#define FIN 128
#define FH 128
#define FOUT 16
#define BN_EPS 1e-5f
#define NB 196  // ceil(50000/256)

typedef short bf16x8 __attribute__((ext_vector_type(8)));
typedef float f32x4 __attribute__((ext_vector_type(4)));

__device__ inline unsigned short tobf16(float f) {
    unsigned int u = __float_as_uint(f);
    u += 0x7fffu + ((u >> 16) & 1u);   // RNE
    return (unsigned short)(u >> 16);
}
__device__ inline float frombf16(unsigned short h) {
    return __uint_as_float(((unsigned int)h) << 16);
}
__device__ inline unsigned packbf(float f0, float f1) {
    return (unsigned)tobf16(f0) | ((unsigned)tobf16(f1) << 16);
}
__device__ inline float lo16(unsigned u) { return __uint_as_float(u << 16); }
__device__ inline float hi16(unsigned u) { return __uint_as_float(u & 0xffff0000u); }

// ---------------- K1: pack x->bf16, W->bf16; deg histogram ----------------
__global__ void pack_deg_kernel(const float* __restrict__ x,
                                const float* __restrict__ Wl1, const float* __restrict__ Wr1,
                                const float* __restrict__ Wl2, const float* __restrict__ Wr2,
                                const int* __restrict__ dst,
                                unsigned short* __restrict__ xb, unsigned short* __restrict__ wb,
                                int* __restrict__ deg) {
    int idx = blockIdx.x * 256 + threadIdx.x;
    if (idx < NNODES * FIN) {
        xb[idx] = tobf16(x[idx]);
    } else if (idx < NNODES * FIN + 36864) {
        int w = idx - NNODES * FIN;
        float v;
        if (w < 16384) v = Wl1[w];
        else if (w < 32768) v = Wr1[w - 16384];
        else if (w < 34816) v = Wl2[w - 32768];
        else v = Wr2[w - 34816];
        wb[w] = tobf16(v);
    }
    if (idx < EEDGES) atomicAdd(&deg[dst[idx]], 1);
}

// ---------------- CSR scan (3-phase) ----------------
__global__ void blocksum_kernel(const int* __restrict__ deg, int* __restrict__ blockSums) {
    int idx = blockIdx.x * 256 + threadIdx.x;
    int v = (idx < NNODES) ? deg[idx] : 0;
    for (int off = 32; off; off >>= 1) v += __shfl_down(v, off, 64);
    __shared__ int sh[4];
    if ((threadIdx.x & 63) == 0) sh[threadIdx.x >> 6] = v;
    __syncthreads();
    if (threadIdx.x == 0) blockSums[blockIdx.x] = sh[0] + sh[1] + sh[2] + sh[3];
}

__global__ void scanblocks_kernel(const int* __restrict__ blockSums, int* __restrict__ blockOff) {
    __shared__ int sh[256];
    int tid = threadIdx.x;
    int v = (tid < NB) ? blockSums[tid] : 0;
    sh[tid] = v;
    __syncthreads();
    for (int off = 1; off < 256; off <<= 1) {
        int t = (tid >= off) ? sh[tid - off] : 0;
        __syncthreads();
        sh[tid] += t;
        __syncthreads();
    }
    if (tid < NB) blockOff[tid] = sh[tid] - v;
}

__global__ void blockscan_kernel(const int* __restrict__ deg, const int* __restrict__ blockOff,
                                 int* __restrict__ rowstart, int* __restrict__ writeptr) {
    __shared__ int sh[256];
    int tid = threadIdx.x;
    int idx = blockIdx.x * 256 + tid;
    int v = (idx < NNODES) ? deg[idx] : 0;
    sh[tid] = v;
    __syncthreads();
    for (int off = 1; off < 256; off <<= 1) {
        int t = (tid >= off) ? sh[tid - off] : 0;
        __syncthreads();
        sh[tid] += t;
        __syncthreads();
    }
    int r = blockOff[blockIdx.x] + sh[tid] - v;
    if (idx < NNODES) { rowstart[idx] = r; writeptr[idx] = r; }
    if (idx == 0) rowstart[NNODES] = EEDGES;
}

__global__ void bucket_kernel(const int* __restrict__ src, const int* __restrict__ dst,
                              int* __restrict__ writeptr, int* __restrict__ srcSorted) {
    int e = blockIdx.x * 256 + threadIdx.x;
    if (e < EEDGES) {
        int p = atomicAdd(&writeptr[dst[e]], 1);
        srcSorted[p] = src[e];
    }
}

// ---------------- gather 128 features (per-node, register accum) ----------------
__global__ void gather_bf16(const unsigned short* __restrict__ feat,
                            const int* __restrict__ rowstart,
                            const int* __restrict__ srcSorted,
                            unsigned short* __restrict__ aggout) {
    int tid = threadIdx.x;
    int i = blockIdx.x * 4 + (tid >> 6);
    int j = tid & 63;
    const unsigned int* fp = (const unsigned int*)feat;
    int k0 = rowstart[i], k1 = rowstart[i + 1];
    float a0 = 0.0f, a1 = 0.0f;
    int k = k0;
    for (; k + 4 <= k1; k += 4) {
        int s0 = srcSorted[k], s1 = srcSorted[k + 1], s2 = srcSorted[k + 2], s3 = srcSorted[k + 3];
        unsigned int u0 = fp[(size_t)s0 * 64 + j];
        unsigned int u1 = fp[(size_t)s1 * 64 + j];
        unsigned int u2 = fp[(size_t)s2 * 64 + j];
        unsigned int u3 = fp[(size_t)s3 * 64 + j];
        a0 += lo16(u0) + lo16(u1) + lo16(u2) + lo16(u3);
        a1 += hi16(u0) + hi16(u1) + hi16(u2) + hi16(u3);
    }
    for (; k < k1; ++k) {
        unsigned int u = fp[(size_t)srcSorted[k] * 64 + j];
        a0 += lo16(u);
        a1 += hi16(u);
    }
    float inv = 1.0f / (float)max(k1 - k0, 1);
    ((unsigned int*)aggout)[(size_t)i * 64 + j] = packbf(a0 * inv, a1 * inv);
}

// ---------------- lin1 MFMA + fused BN column partials ----------------
__global__ void lin1_mfma(const unsigned short* __restrict__ aggb,
                          const unsigned short* __restrict__ xb,
                          const unsigned short* __restrict__ wl,
                          const unsigned short* __restrict__ wr,
                          const float* __restrict__ bias,
                          unsigned short* __restrict__ hb,
                          float* __restrict__ bnsum, float* __restrict__ bnsq) {
    __shared__ float bps[128];
    __shared__ float bpq[128];
    int tid = threadIdx.x;
    if (tid < 128) { bps[tid] = 0.0f; bpq[tid] = 0.0f; }
    __syncthreads();
    int wave = tid >> 6;
    int lane = tid & 63;
    int row0 = blockIdx.x * 64 + wave * 16;
    int lrow = lane & 15;
    int kg = lane >> 4;
    int arow = min(row0 + lrow, NNODES - 1);
    f32x4 acc[8] = {};
    #pragma unroll
    for (int ks = 0; ks < 4; ++ks) {
        bf16x8 a = *(const bf16x8*)(aggb + (size_t)arow * 128 + ks * 32 + kg * 8);
        #pragma unroll
        for (int nf = 0; nf < 8; ++nf) {
            bf16x8 b = *(const bf16x8*)(wl + (size_t)(nf * 16 + lrow) * 128 + ks * 32 + kg * 8);
            acc[nf] = __builtin_amdgcn_mfma_f32_16x16x32_bf16(a, b, acc[nf], 0, 0, 0);
        }
    }
    #pragma unroll
    for (int ks = 0; ks < 4; ++ks) {
        bf16x8 a = *(const bf16x8*)(xb + (size_t)arow * 128 + ks * 32 + kg * 8);
        #pragma unroll
        for (int nf = 0; nf < 8; ++nf) {
            bf16x8 b = *(const bf16x8*)(wr + (size_t)(nf * 16 + lrow) * 128 + ks * 32 + kg * 8);
            acc[nf] = __builtin_amdgcn_mfma_f32_16x16x32_bf16(a, b, acc[nf], 0, 0, 0);
        }
    }
    #pragma unroll
    for (int nf = 0; nf < 8; ++nf) {
        float b = bias[nf * 16 + lrow];
        float s = 0.0f, q = 0.0f;
        #pragma unroll
        for (int r = 0; r < 4; ++r) {
            int row = row0 + kg * 4 + r;
            if (row < NNODES) {
                unsigned short hv = tobf16(acc[nf][r] + b);
                float vr = frombf16(hv);
                hb[(size_t)row * 128 + nf * 16 + lrow] = hv;
                s += vr; q += vr * vr;
            }
        }
        s += __shfl_xor(s, 16); s += __shfl_xor(s, 32);
        q += __shfl_xor(q, 16); q += __shfl_xor(q, 32);
        if (lane < 16) {
            atomicAdd(&bps[nf * 16 + lane], s);
            atomicAdd(&bpq[nf * 16 + lane], q);
        }
    }
    __syncthreads();
    if (tid < 128) {
        atomicAdd(&bnsum[tid], bps[tid]);
        atomicAdd(&bnsq[tid], bpq[tid]);
    }
}

// ---------------- BN apply + PReLU + residual (bf16 x), in place on hb ----------------
__global__ void bn_apply_kernel(unsigned short* __restrict__ hb,
                                const unsigned short* __restrict__ xb,
                                const float* __restrict__ gamma, const float* __restrict__ beta,
                                const float* __restrict__ aptr,
                                const float* __restrict__ bnsum, const float* __restrict__ bnsq) {
    int idx = blockIdx.x * 256 + threadIdx.x;
    if (idx >= NNODES * FH) return;
    int j = idx & 127;
    const float invN = 1.0f / (float)NNODES;
    float mean = bnsum[j] * invN;
    float var = bnsq[j] * invN - mean * mean;
    float istd = rsqrtf(var + BN_EPS);
    float v = frombf16(hb[idx]);
    v = gamma[j] * (v - mean) * istd + beta[j];
    float a = aptr[0];
    v = (v >= 0.0f) ? v : a * v;
    hb[idx] = tobf16(v + frombf16(xb[idx]));
}

// ---------------- y2 = hb @ Wl2^T (bf16 out, [N,16]) ----------------
__global__ void lin2a_kernel(const unsigned short* __restrict__ hb,
                             const unsigned short* __restrict__ wl,
                             unsigned short* __restrict__ y2) {
    int wave = threadIdx.x >> 6;
    int lane = threadIdx.x & 63;
    int row0 = blockIdx.x * 64 + wave * 16;
    int lrow = lane & 15;
    int kg = lane >> 4;
    int arow = min(row0 + lrow, NNODES - 1);
    f32x4 acc = {};
    #pragma unroll
    for (int ks = 0; ks < 4; ++ks) {
        bf16x8 a = *(const bf16x8*)(hb + (size_t)arow * 128 + ks * 32 + kg * 8);
        bf16x8 b = *(const bf16x8*)(wl + (size_t)lrow * 128 + ks * 32 + kg * 8);
        acc = __builtin_amdgcn_mfma_f32_16x16x32_bf16(a, b, acc, 0, 0, 0);
    }
    #pragma unroll
    for (int r = 0; r < 4; ++r) {
        int row = row0 + kg * 4 + r;
        if (row < NNODES)
            y2[(size_t)row * 16 + lrow] = tobf16(acc[r]);
    }
}

// ---------------- gather 16 features (per-node CSR; 8 lanes/edge, 8 edges in flight) --------
__global__ void gather16_kernel(const unsigned short* __restrict__ y2,
                                const int* __restrict__ rowstart,
                                const int* __restrict__ srcSorted,
                                unsigned short* __restrict__ agg2) {
    int tid = threadIdx.x;
    int i = blockIdx.x * 4 + (tid >> 6);
    int lane = tid & 63;
    int e = lane >> 3;       // edge slot 0..7
    int j = lane & 7;        // uint index within the 8-uint (16-bf16) row
    const unsigned int* yp = (const unsigned int*)y2;
    int k0 = rowstart[i], k1 = rowstart[i + 1];
    float a0 = 0.0f, a1 = 0.0f;
    for (int k = k0; k < k1; k += 8) {
        int kk = k + e;
        if (kk < k1) {
            unsigned u = yp[(size_t)srcSorted[kk] * 8 + j];
            a0 += lo16(u);
            a1 += hi16(u);
        }
    }
    // reduce across the 8 edge slots (lanes with same j, e = 0..7)
    a0 += __shfl_xor(a0, 8);  a1 += __shfl_xor(a1, 8);
    a0 += __shfl_xor(a0, 16); a1 += __shfl_xor(a1, 16);
    a0 += __shfl_xor(a0, 32); a1 += __shfl_xor(a1, 32);
    if (e == 0) {
        float inv = 1.0f / (float)max(k1 - k0, 1);
        ((unsigned int*)agg2)[(size_t)i * 8 + j] = packbf(a0 * inv, a1 * inv);
    }
}

// ---------------- out = agg2 + hb@Wr2^T + bl2 -> log_softmax ----------------
__global__ void lin2b_kernel(const unsigned short* __restrict__ agg2,
                             const unsigned short* __restrict__ hb,
                             const unsigned short* __restrict__ wr,
                             const float* __restrict__ bias,
                             float* __restrict__ out) {
    int wave = threadIdx.x >> 6;
    int lane = threadIdx.x & 63;
    int row0 = blockIdx.x * 64 + wave * 16;
    int lrow = lane & 15;
    int kg = lane >> 4;
    int arow = min(row0 + lrow, NNODES - 1);
    f32x4 acc = {};
    #pragma unroll
    for (int ks = 0; ks < 4; ++ks) {
        bf16x8 a = *(const bf16x8*)(hb + (size_t)arow * 128 + ks * 32 + kg * 8);
        bf16x8 b = *(const bf16x8*)(wr + (size_t)lrow * 128 + ks * 32 + kg * 8);
        acc = __builtin_amdgcn_mfma_f32_16x16x32_bf16(a, b, acc, 0, 0, 0);
    }
    float bl = bias[lrow];
    #pragma unroll
    for (int r = 0; r < 4; ++r) {
        int row = row0 + kg * 4 + r;
        int rowc = min(row, NNODES - 1);
        float v = acc[r] + bl + frombf16(agg2[(size_t)rowc * 16 + lrow]);
        float m = v;
        for (int s = 1; s < 16; s <<= 1) m = fmaxf(m, __shfl_xor(m, s, 16));
        float ex = expf(v - m);
        float se = ex;
        for (int s = 1; s < 16; s <<= 1) se += __shfl_xor(se, s, 16);
        if (row < NNODES)
            out[(size_t)row * FOUT + lrow] = v - m - logf(se);
    }
}

extern "C" void kernel_launch(void* const* d_in, const int* in_sizes, int n_in,
                              void* d_out, int out_size, void* d_ws, size_t ws_size,
                              hipStream_t stream) {
    const float* x    = (const float*)d_in[0];
    const int*   ei   = (const int*)d_in[1];
    const int*   src  = ei;
    const int*   dst  = ei + EEDGES;
    const float* Wl1  = (const float*)d_in[2];
    const float* bl1  = (const float*)d_in[3];
    const float* Wr1  = (const float*)d_in[4];
    const float* Wl2  = (const float*)d_in[5];
    const float* bl2  = (const float*)d_in[6];
    const float* Wr2  = (const float*)d_in[7];
    const float* gamma= (const float*)d_in[8];
    const float* beta = (const float*)d_in[9];
    const float* a    = (const float*)d_in[10];
    float* out = (float*)d_out;

    char* W = (char*)d_ws;
    unsigned short* xb    = (unsigned short*)(W + 0);           // 12,800,000 B
    unsigned short* hb    = (unsigned short*)(W + 12800000);    // 12,800,000 B
    unsigned short* aggb  = (unsigned short*)(W + 25600000);    // 12,800,000 B (layer1)
    unsigned short* y2b   = (unsigned short*)(W + 25600000);    // 1,600,000 B (overlays aggb)
    unsigned short* agg2b = (unsigned short*)(W + 27200000);    // 1,600,000 B (overlays aggb)
    unsigned short* wb    = (unsigned short*)(W + 38400000);    // 73,728 B
    int* deg      = (int*)(W + 38473728);                       // 200,000 B
    float* bnsum  = (float*)(W + 38673728);                     // 512 B
    float* bnsq   = (float*)(W + 38674240);                     // 512 B
    int* rowstart = (int*)(W + 38674752);                       // 200,016 B
    int* writeptr = (int*)(W + 38874768);                       // 200,000 B
    int* srcSorted= (int*)(W + 39074768);                       // 3,200,000 B
    int* blockSums= (int*)(W + 42274768);                       // 784 B
    int* blockOff = (int*)(W + 42275552);                       // 784 B

    unsigned short* wl1b = wb;
    unsigned short* wr1b = wb + 16384;
    unsigned short* wl2b = wb + 32768;
    unsigned short* wr2b = wb + 34816;

    // zero deg + bnsum + bnsq (contiguous: 201,024 B)
    hipMemsetAsync(deg, 0, (size_t)201024, stream);

    pack_deg_kernel<<<25145, 256, 0, stream>>>(x, Wl1, Wr1, Wl2, Wr2, dst, xb, wb, deg);
    blocksum_kernel<<<NB, 256, 0, stream>>>(deg, blockSums);
    scanblocks_kernel<<<1, 256, 0, stream>>>(blockSums, blockOff);
    blockscan_kernel<<<NB, 256, 0, stream>>>(deg, blockOff, rowstart, writeptr);
    bucket_kernel<<<EEDGES / 256, 256, 0, stream>>>(src, dst, writeptr, srcSorted);

    // layer 1
    gather_bf16<<<NNODES / 4, 256, 0, stream>>>(xb, rowstart, srcSorted, aggb);
    lin1_mfma<<<782, 256, 0, stream>>>(aggb, xb, wl1b, wr1b, bl1, hb, bnsum, bnsq);
    bn_apply_kernel<<<25000, 256, 0, stream>>>(hb, xb, gamma, beta, a, bnsum, bnsq);

    // layer 2 (transform-then-aggregate)
    lin2a_kernel<<<782, 256, 0, stream>>>(hb, wl2b, y2b);
    gather16_kernel<<<NNODES / 4, 256, 0, stream>>>(y2b, rowstart, srcSorted, agg2b);
    lin2b_kernel<<<782, 256, 0, stream>>>(agg2b, hb, wr2b, bl2, out);
}